// Round 4
// baseline (948.502 us; speedup 1.0000x reference)
//
#include <hip/hip_runtime.h>
#include <math.h>

// B=8, C=128, N=4096, d=16, groups=32
// attn: S^T = K @ Q^T via mfma_32x32x16_bf16 (coalesced global frags, no LDS),
//       P = exp2(S^T) (no-max softmax; Q pre-scaled by 0.25*log2e),
//       P^T B-frags built in-register via half-wave shfl_xor(32) exchange,
//       O^T = V @ P^T with V in TILED layout vt[b][j>>4][c][j&15] so A-frag
//       loads are coalesced 1KB segments. 8 j-chunk waves/block, zero barriers
//       in the j-loop; block-level combine via LDS ds_add_f32.

typedef short v8s __attribute__((ext_vector_type(8)));   // 8 bf16 = 4 VGPRs
typedef float v16f __attribute__((ext_vector_type(16))); // 32x32 acc

__device__ __forceinline__ unsigned short f2bf_rne(float f) {
  unsigned u = __float_as_uint(f);
  u += 0x7fffu + ((u >> 16) & 1u);
  return (unsigned short)(u >> 16);
}

__device__ __forceinline__ v8s mk8(unsigned a, unsigned b, unsigned c, unsigned d) {
  union { unsigned u[4]; v8s s; } x;
  x.u[0] = a; x.u[1] = b; x.u[2] = c; x.u[3] = d;
  return x.s;
}

// pack two fp32 -> dword of 2 bf16 (truncation) in ONE v_perm_b32
__device__ __forceinline__ unsigned pack_trunc(float hi, float lo) {
  return __builtin_amdgcn_perm(__float_as_uint(hi), __float_as_uint(lo), 0x07060302u);
}

// tiled V element index: [b][j>>4][c][j&15]
#define VT(b, n, c) (((((size_t)(b) * 256 + ((n) >> 4)) << 7) + (c)) * 16 + ((n) & 15))

// ws byte offsets
#define WSB_MURS   0u
#define WSB_WCATB  4096u       // 160*128 bf16 = 40960
#define WSB_BCAT   49152u      // 160 f32
#define WSB_PWB    65536u      // 128*128 bf16 = 32768
#define WSB_QBF    131072u     // 8*4096*16 bf16 = 1 MB
#define WSB_KBF    1310720u    // 1 MB
#define WSB_VBF    2621440u    // 8 MB (tiled)
#define WSB_ABF    11534336u   // 8 MB

// ---------------------------------------------------------------------------
__global__ void prep_kernel(const float* __restrict__ qw, const float* __restrict__ qb,
                            const float* __restrict__ kw, const float* __restrict__ kb,
                            const float* __restrict__ vw, const float* __restrict__ vb,
                            const float* __restrict__ pw,
                            unsigned short* __restrict__ wcatb, float* __restrict__ bcat,
                            unsigned short* __restrict__ pwb) {
  const float qs = 0.36067376022224085f;  // 0.25 * log2(e)
  int idx = blockIdx.x * 256 + threadIdx.x;
  if (idx < 160 * 128) {
    int o = idx >> 7, c = idx & 127;
    float val;
    if (o < 16)       val = qw[o * 128 + c] * qs;
    else if (o < 32)  val = kw[(o - 16) * 128 + c];
    else              val = vw[(o - 32) * 128 + c];
    wcatb[idx] = f2bf_rne(val);
  } else if (idx < 160 * 128 + 160) {
    int o = idx - 160 * 128;
    bcat[o] = (o < 16) ? qb[o] * qs : (o < 32) ? kb[o - 16] : vb[o - 32];
  } else if (idx < 160 * 128 + 160 + 128 * 128) {
    int j = idx - (160 * 128 + 160);
    pwb[j] = f2bf_rne(pw[j]);
  }
}

// ---------------------------------------------------------------------------
__global__ __launch_bounds__(512)
void gn_stats_kernel(const float* __restrict__ x, float* __restrict__ mu_rs) {
  int bg = blockIdx.x;  // 0..255
  const float4* xp = (const float4*)(x + (size_t)bg * 16384);
  float s = 0.f, ss = 0.f;
  for (int i = threadIdx.x; i < 4096; i += 512) {
    float4 v = xp[i];
    s  += v.x + v.y + v.z + v.w;
    ss += v.x * v.x + v.y * v.y + v.z * v.z + v.w * v.w;
  }
  for (int off = 32; off > 0; off >>= 1) {
    s  += __shfl_down(s, off, 64);
    ss += __shfl_down(ss, off, 64);
  }
  __shared__ float red[16];
  int lane = threadIdx.x & 63, wid = threadIdx.x >> 6;
  if (lane == 0) { red[wid * 2] = s; red[wid * 2 + 1] = ss; }
  __syncthreads();
  if (threadIdx.x == 0) {
    float S = 0.f, SS = 0.f;
    for (int w = 0; w < 8; ++w) { S += red[w * 2]; SS += red[w * 2 + 1]; }
    float mu  = S * (1.0f / 16384.0f);
    float var = SS * (1.0f / 16384.0f) - mu * mu;
    float rs  = rsqrtf(var + 1e-5f);
    mu_rs[bg * 2]     = mu;
    mu_rs[bg * 2 + 1] = rs;
  }
}

// ---------------------------------------------------------------------------
// QKV as MFMA GEMM, GN fused. Block 512 thr (8 waves), n-tile 64.
// wave w: nsub = w&1 (32 cols), og = w>>1: og0 -> ot{0,1}, og1 -> ot{2},
// og2 -> ot{3}, og3 -> ot{4}.   (ot0 = q+k rows 0..31; ot1..4 = v rows.)
// V written in tiled layout VT. Grid (64, 8) = 4096 waves.
// ---------------------------------------------------------------------------
__global__ __launch_bounds__(512)
void qkv_kernel(const float* __restrict__ x, const float* __restrict__ gnw,
                const float* __restrict__ gnb, const float* __restrict__ mu_rs,
                const unsigned short* __restrict__ wcatb, const float* __restrict__ bcat,
                unsigned short* __restrict__ qbf, unsigned short* __restrict__ kbf,
                unsigned short* __restrict__ vbf) {
  __shared__ float scs[128], shs[128], bsh[160];
  const int b = blockIdx.y, nb = blockIdx.x * 64, t = threadIdx.x;
  const int w = t >> 6, lane = t & 63, h = lane >> 5, l = lane & 31;
  const int nsub = w & 1, og = w >> 1;
  if (t < 128) {
    float mu = mu_rs[(b * 32 + (t >> 2)) * 2];
    float rs = mu_rs[(b * 32 + (t >> 2)) * 2 + 1];
    float gw = gnw[t], gb = gnb[t];
    scs[t] = rs * gw; shs[t] = gb - mu * rs * gw;
  }
  if (t < 160) bsh[t] = bcat[t];
  __syncthreads();

  const int n = nb + nsub * 32 + l;
  const float* xb = x + ((size_t)b * 128 << 12);
  const int not_ = (og == 0) ? 2 : 1;       // accumulators this wave
  const int otbase = (og == 0) ? 0 : og + 1; // ot index of acc[0]

  v16f acc[2];
#pragma unroll
  for (int a2 = 0; a2 < 2; ++a2)
#pragma unroll
    for (int r = 0; r < 16; ++r) acc[a2][r] = 0.f;

  for (int ks = 0; ks < 8; ++ks) {
    const int c0 = ks * 16 + 8 * h;
    unsigned fd[4];
#pragma unroll
    for (int p = 0; p < 4; ++p) {
      int ca = c0 + 2 * p, cb2 = ca + 1;
      float h0 = xb[((size_t)ca << 12) + n] * scs[ca] + shs[ca];
      float h1 = xb[((size_t)cb2 << 12) + n] * scs[cb2] + shs[cb2];
      fd[p] = (unsigned)f2bf_rne(h0) | ((unsigned)f2bf_rne(h1) << 16);
    }
    v8s bf = mk8(fd[0], fd[1], fd[2], fd[3]);
    {
      v8s af = *(const v8s*)(wcatb + (otbase * 32 + l) * 128 + ks * 16 + 8 * h);
      acc[0] = __builtin_amdgcn_mfma_f32_32x32x16_bf16(af, bf, acc[0], 0, 0, 0);
    }
    if (og == 0) {
      v8s af = *(const v8s*)(wcatb + (32 + l) * 128 + ks * 16 + 8 * h);
      acc[1] = __builtin_amdgcn_mfma_f32_32x32x16_bf16(af, bf, acc[1], 0, 0, 0);
    }
  }

  // epilogue
  if (og == 0) {
    const size_t nqk = ((size_t)b * 4096 + n) << 4;
#pragma unroll
    for (int r = 0; r < 16; ++r) {
      int o = 4 * h + (r & 3) + 8 * (r >> 2);
      unsigned short bv = f2bf_rne(acc[0][r] + bsh[o]);
      if (o < 16) qbf[nqk + o] = bv; else kbf[nqk + o - 16] = bv;
    }
#pragma unroll
    for (int r = 0; r < 16; ++r) {
      int o = 32 + 4 * h + (r & 3) + 8 * (r >> 2);
      vbf[VT(b, n, o - 32)] = f2bf_rne(acc[1][r] + bsh[o]);
    }
  } else {
#pragma unroll
    for (int r = 0; r < 16; ++r) {
      int o = otbase * 32 + 4 * h + (r & 3) + 8 * (r >> 2);
      vbf[VT(b, n, o - 32)] = f2bf_rne(acc[0][r] + bsh[o]);
    }
  }
}

// ---------------------------------------------------------------------------
// Flash attention, barrier-free j-loop, coalesced V via tiled layout.
// Block 512 thr (8 waves), i-tile 64, wave w owns j-chunk [w*512, w*512+512).
// ---------------------------------------------------------------------------
__global__ __launch_bounds__(512, 4)
void attn_kernel(const unsigned short* __restrict__ qbf,
                 const unsigned short* __restrict__ kbf,
                 const unsigned short* __restrict__ vbf,
                 unsigned short* __restrict__ abf) {
  __shared__ float O_lds[128 * 64];
  __shared__ float l_lds[64];
  const int b = blockIdx.y, i0 = blockIdx.x * 64;
  const int t = threadIdx.x;
  const int w = t >> 6, lane = t & 63, h = lane >> 5, l = lane & 31;

  for (int idx = t; idx < 128 * 64; idx += 512) O_lds[idx] = 0.f;
  if (t < 64) l_lds[t] = 0.f;
  __syncthreads();

  v16f zc;
#pragma unroll
  for (int r = 0; r < 16; ++r) zc[r] = 0.f;

  // Q B-frags: B[k=d][n=i], n=lane&31, k=8h+e -> b128 from [B,N,16]
  const v8s qf0 = *(const v8s*)(qbf + (((size_t)(b * 4096 + i0 + l)) << 4) + 8 * h);
  const v8s qf1 = *(const v8s*)(qbf + (((size_t)(b * 4096 + i0 + 32 + l)) << 4) + 8 * h);

  v16f acc[4][2];
#pragma unroll
  for (int ct = 0; ct < 4; ++ct)
#pragma unroll
    for (int ti = 0; ti < 2; ++ti)
#pragma unroll
      for (int r = 0; r < 16; ++r) acc[ct][ti][r] = 0.f;
  float ls0 = 0.f, ls1 = 0.f;

  const unsigned short* kb_ = kbf + ((size_t)b << 16);
  const unsigned short* vt_ = vbf + ((size_t)b << 19);  // b*256*128*16
  const int jbeg = w * 512;

  for (int tile = 0; tile < 16; ++tile) {
    const int j0 = jbeg + tile * 32;
    // K A-frag: A[m=j][k=d] (coalesced 2KB)
    v8s kf = *(const v8s*)(kb_ + (((size_t)(j0 + l)) << 4) + 8 * h);

    unsigned G[2][8];
    {
      v16f st = __builtin_amdgcn_mfma_f32_32x32x16_bf16(kf, qf0, zc, 0, 0, 0);
      float p[16];
#pragma unroll
      for (int r = 0; r < 16; ++r) { p[r] = __builtin_amdgcn_exp2f(st[r]); ls0 += p[r]; }
#pragma unroll
      for (int g = 0; g < 4; ++g) {
        G[0][2 * g]     = pack_trunc(p[4 * g + 1], p[4 * g]);
        G[0][2 * g + 1] = pack_trunc(p[4 * g + 3], p[4 * g + 2]);
      }
    }
    {
      v16f st = __builtin_amdgcn_mfma_f32_32x32x16_bf16(kf, qf1, zc, 0, 0, 0);
      float p[16];
#pragma unroll
      for (int r = 0; r < 16; ++r) { p[r] = __builtin_amdgcn_exp2f(st[r]); ls1 += p[r]; }
#pragma unroll
      for (int g = 0; g < 4; ++g) {
        G[1][2 * g]     = pack_trunc(p[4 * g + 1], p[4 * g]);
        G[1][2 * g + 1] = pack_trunc(p[4 * g + 3], p[4 * g + 2]);
      }
    }

    unsigned T[2][8];
#pragma unroll
    for (int ti = 0; ti < 2; ++ti)
#pragma unroll
      for (int q = 0; q < 8; ++q)
        T[ti][q] = (unsigned)__shfl_xor((int)G[ti][q], 32, 64);

    // B-frag for PV kstep ks: lo2 = quad g=2ks+h from half0, hi2 = same g from half1
    unsigned pf[2][2][4];
#pragma unroll
    for (int ti = 0; ti < 2; ++ti)
#pragma unroll
      for (int ks = 0; ks < 2; ++ks) {
        pf[ti][ks][0] = h ? T[ti][(2 * ks + 1) * 2]     : G[ti][(2 * ks) * 2];
        pf[ti][ks][1] = h ? T[ti][(2 * ks + 1) * 2 + 1] : G[ti][(2 * ks) * 2 + 1];
        pf[ti][ks][2] = h ? G[ti][(2 * ks + 1) * 2]     : T[ti][(2 * ks) * 2];
        pf[ti][ks][3] = h ? G[ti][(2 * ks + 1) * 2 + 1] : T[ti][(2 * ks) * 2 + 1];
      }

#pragma unroll
    for (int ks = 0; ks < 2; ++ks) {
      v8s pf0 = mk8(pf[0][ks][0], pf[0][ks][1], pf[0][ks][2], pf[0][ks][3]);
      v8s pf1 = mk8(pf[1][ks][0], pf[1][ks][1], pf[1][ks][2], pf[1][ks][3]);
      const size_t chunk = (size_t)((j0 >> 4) + ks) << 7;  // *128
#pragma unroll
      for (int ct = 0; ct < 4; ++ct) {
        // V A-frag: A[m=c][k=j], coalesced 1KB from tiled layout
        v8s vf = *(const v8s*)(vt_ + ((chunk + ct * 32 + l) << 4) + 8 * h);
        acc[ct][0] = __builtin_amdgcn_mfma_f32_32x32x16_bf16(vf, pf0, acc[ct][0], 0, 0, 0);
        acc[ct][1] = __builtin_amdgcn_mfma_f32_32x32x16_bf16(vf, pf1, acc[ct][1], 0, 0, 0);
      }
    }
  }

  // combine partials across the 8 j-chunk waves
  atomicAdd(&l_lds[l], ls0);
  atomicAdd(&l_lds[32 + l], ls1);
#pragma unroll
  for (int ct = 0; ct < 4; ++ct)
#pragma unroll
    for (int ti = 0; ti < 2; ++ti)
#pragma unroll
      for (int r = 0; r < 16; ++r) {
        int c = ct * 32 + 4 * h + (r & 3) + 8 * (r >> 2);
        int i = ti * 32 + l;
        atomicAdd(&O_lds[c * 64 + i], acc[ct][ti][r]);
      }
  __syncthreads();

  // normalize + store O^T -> abf [B,C,N] bf16
  const int i4 = (t & 15) * 4, cb = t >> 4;
  float4 l4 = *(float4*)&l_lds[i4];
  float lix = 1.f / l4.x, liy = 1.f / l4.y, liz = 1.f / l4.z, liw = 1.f / l4.w;
  for (int cc = cb; cc < 128; cc += 32) {
    float4 o4 = *(float4*)&O_lds[cc * 64 + i4];
    unsigned d0 = (unsigned)f2bf_rne(o4.x * lix) | ((unsigned)f2bf_rne(o4.y * liy) << 16);
    unsigned d1 = (unsigned)f2bf_rne(o4.z * liz) | ((unsigned)f2bf_rne(o4.w * liw) << 16);
    uint2 st2; st2.x = d0; st2.y = d1;
    *(uint2*)(abf + (((size_t)(b * 128 + cc)) << 12) + i0 + i4) = st2;
  }
}

// ---------------------------------------------------------------------------
// proj as MFMA GEMM + bias + residual. Block 512 thr (8 waves), n-tile 64:
// nsub = w&1, ot = w>>1 (one 32-row o-tile per wave). Grid (64, 8).
// ---------------------------------------------------------------------------
__global__ __launch_bounds__(512)
void proj_kernel(const unsigned short* __restrict__ abf, const unsigned short* __restrict__ pwb,
                 const float* __restrict__ pb, const float* __restrict__ x,
                 float* __restrict__ out) {
  __shared__ float pbs[128];
  const int b = blockIdx.y, nb = blockIdx.x * 64, t = threadIdx.x;
  const int w = t >> 6, lane = t & 63, h = lane >> 5, l = lane & 31;
  const int nsub = w & 1, ot = w >> 1;
  if (t < 128) pbs[t] = pb[t];
  __syncthreads();

  const int n = nb + nsub * 32 + l;
  const unsigned short* ab = abf + (((size_t)b * 128) << 12);
  v16f acc;
#pragma unroll
  for (int r = 0; r < 16; ++r) acc[r] = 0.f;

  for (int ks = 0; ks < 8; ++ks) {
    const int c0 = ks * 16 + 8 * h;
    unsigned fd[4];
#pragma unroll
    for (int p = 0; p < 4; ++p) {
      unsigned u0 = ab[((size_t)(c0 + 2 * p) << 12) + n];
      unsigned u1 = ab[((size_t)(c0 + 2 * p + 1) << 12) + n];
      fd[p] = u0 | (u1 << 16);
    }
    v8s bf = mk8(fd[0], fd[1], fd[2], fd[3]);
    v8s af = *(const v8s*)(pwb + (ot * 32 + l) * 128 + ks * 16 + 8 * h);
    acc = __builtin_amdgcn_mfma_f32_32x32x16_bf16(af, bf, acc, 0, 0, 0);
  }

#pragma unroll
  for (int r = 0; r < 16; ++r) {
    int e = ot * 32 + 4 * h + (r & 3) + 8 * (r >> 2);
    size_t idx = ((size_t)(b * 128 + e) << 12) + n;
    out[idx] = acc[r] + pbs[e] + x[idx];
  }
}

// ---------------------------------------------------------------------------
extern "C" void kernel_launch(void* const* d_in, const int* in_sizes, int n_in,
                              void* d_out, int out_size, void* d_ws, size_t ws_size,
                              hipStream_t stream) {
  const float* x   = (const float*)d_in[0];
  const float* gnw = (const float*)d_in[1];
  const float* gnb = (const float*)d_in[2];
  const float* qw  = (const float*)d_in[3];
  const float* qb  = (const float*)d_in[4];
  const float* kw  = (const float*)d_in[5];
  const float* kb  = (const float*)d_in[6];
  const float* vw  = (const float*)d_in[7];
  const float* vb  = (const float*)d_in[8];
  const float* pw  = (const float*)d_in[9];
  const float* pb  = (const float*)d_in[10];
  float* out = (float*)d_out;
  char* ws = (char*)d_ws;

  float* mu_rs = (float*)(ws + WSB_MURS);
  unsigned short* wcatb = (unsigned short*)(ws + WSB_WCATB);
  float* bcat = (float*)(ws + WSB_BCAT);
  unsigned short* pwb = (unsigned short*)(ws + WSB_PWB);
  unsigned short* qbf = (unsigned short*)(ws + WSB_QBF);
  unsigned short* kbf = (unsigned short*)(ws + WSB_KBF);
  unsigned short* vbf = (unsigned short*)(ws + WSB_VBF);
  unsigned short* abf = (unsigned short*)(ws + WSB_ABF);

  hipLaunchKernelGGL(prep_kernel, dim3(145), dim3(256), 0, stream,
                     qw, qb, kw, kb, vw, vb, pw, wcatb, bcat, pwb);
  hipLaunchKernelGGL(gn_stats_kernel, dim3(256), dim3(512), 0, stream, x, mu_rs);
  hipLaunchKernelGGL(qkv_kernel, dim3(64, 8), dim3(512), 0, stream,
                     x, gnw, gnb, mu_rs, wcatb, bcat, qbf, kbf, vbf);
  hipLaunchKernelGGL(attn_kernel, dim3(64, 8), dim3(512), 0, stream,
                     qbf, kbf, vbf, abf);
  hipLaunchKernelGGL(proj_kernel, dim3(64, 8), dim3(512), 0, stream,
                     abf, pwb, pb, x, out);
}

// Round 5
// 284.918 us; speedup vs baseline: 3.3290x; 3.3290x over previous
//
#include <hip/hip_runtime.h>
#include <math.h>

// B=8, C=128, N=4096, d=16, groups=32
// attn: S^T = K @ Q^T via mfma_32x32x16_bf16 (coalesced global frags, no LDS),
//       P = exp2(S^T) (no-max softmax; Q pre-scaled by 0.25*log2e),
//       P^T B-frags built in-register via half-wave shfl_xor(32) exchange,
//       O^T = V @ P^T with V in TILED layout vt[b][j>>4][c][j&15] (coalesced).
//       512-thr block = 8 waves, wave = (j-chunk of 1024) x (i-subtile of 32):
//       acc[4] (64 f32) per wave -> no spill. NO min-waves launch bound
//       (R4 post-mortem: __launch_bounds__(512,4) forced VGPR=64 -> 2.4 GB
//       scratch spill). Zero barriers in j-loop; LDS ds_add combine at end.

typedef short v8s __attribute__((ext_vector_type(8)));   // 8 bf16 = 4 VGPRs
typedef float v16f __attribute__((ext_vector_type(16))); // 32x32 acc

__device__ __forceinline__ unsigned short f2bf_rne(float f) {
  unsigned u = __float_as_uint(f);
  u += 0x7fffu + ((u >> 16) & 1u);
  return (unsigned short)(u >> 16);
}

__device__ __forceinline__ v8s mk8(unsigned a, unsigned b, unsigned c, unsigned d) {
  union { unsigned u[4]; v8s s; } x;
  x.u[0] = a; x.u[1] = b; x.u[2] = c; x.u[3] = d;
  return x.s;
}

// pack two fp32 -> dword of 2 bf16 (truncation) in ONE v_perm_b32
__device__ __forceinline__ unsigned pack_trunc(float hi, float lo) {
  return __builtin_amdgcn_perm(__float_as_uint(hi), __float_as_uint(lo), 0x07060302u);
}

// tiled V element index: [b][j>>4][c][j&15]
#define VT(b, n, c) (((((size_t)(b) * 256 + ((n) >> 4)) << 7) + (c)) * 16 + ((n) & 15))

// ws byte offsets
#define WSB_MURS   0u
#define WSB_WCATB  4096u       // 160*128 bf16 = 40960
#define WSB_BCAT   49152u      // 160 f32
#define WSB_PWB    65536u      // 128*128 bf16 = 32768
#define WSB_QBF    131072u     // 8*4096*16 bf16 = 1 MB
#define WSB_KBF    1310720u    // 1 MB
#define WSB_VBF    2621440u    // 8 MB (tiled)
#define WSB_ABF    11534336u   // 8 MB

// ---------------------------------------------------------------------------
__global__ void prep_kernel(const float* __restrict__ qw, const float* __restrict__ qb,
                            const float* __restrict__ kw, const float* __restrict__ kb,
                            const float* __restrict__ vw, const float* __restrict__ vb,
                            const float* __restrict__ pw,
                            unsigned short* __restrict__ wcatb, float* __restrict__ bcat,
                            unsigned short* __restrict__ pwb) {
  const float qs = 0.36067376022224085f;  // 0.25 * log2(e)
  int idx = blockIdx.x * 256 + threadIdx.x;
  if (idx < 160 * 128) {
    int o = idx >> 7, c = idx & 127;
    float val;
    if (o < 16)       val = qw[o * 128 + c] * qs;
    else if (o < 32)  val = kw[(o - 16) * 128 + c];
    else              val = vw[(o - 32) * 128 + c];
    wcatb[idx] = f2bf_rne(val);
  } else if (idx < 160 * 128 + 160) {
    int o = idx - 160 * 128;
    bcat[o] = (o < 16) ? qb[o] * qs : (o < 32) ? kb[o - 16] : vb[o - 32];
  } else if (idx < 160 * 128 + 160 + 128 * 128) {
    int j = idx - (160 * 128 + 160);
    pwb[j] = f2bf_rne(pw[j]);
  }
}

// ---------------------------------------------------------------------------
__global__ __launch_bounds__(512)
void gn_stats_kernel(const float* __restrict__ x, float* __restrict__ mu_rs) {
  int bg = blockIdx.x;  // 0..255
  const float4* xp = (const float4*)(x + (size_t)bg * 16384);
  float s = 0.f, ss = 0.f;
  for (int i = threadIdx.x; i < 4096; i += 512) {
    float4 v = xp[i];
    s  += v.x + v.y + v.z + v.w;
    ss += v.x * v.x + v.y * v.y + v.z * v.z + v.w * v.w;
  }
  for (int off = 32; off > 0; off >>= 1) {
    s  += __shfl_down(s, off, 64);
    ss += __shfl_down(ss, off, 64);
  }
  __shared__ float red[16];
  int lane = threadIdx.x & 63, wid = threadIdx.x >> 6;
  if (lane == 0) { red[wid * 2] = s; red[wid * 2 + 1] = ss; }
  __syncthreads();
  if (threadIdx.x == 0) {
    float S = 0.f, SS = 0.f;
    for (int w = 0; w < 8; ++w) { S += red[w * 2]; SS += red[w * 2 + 1]; }
    float mu  = S * (1.0f / 16384.0f);
    float var = SS * (1.0f / 16384.0f) - mu * mu;
    float rs  = rsqrtf(var + 1e-5f);
    mu_rs[bg * 2]     = mu;
    mu_rs[bg * 2 + 1] = rs;
  }
}

// ---------------------------------------------------------------------------
// QKV as MFMA GEMM, GN fused. Block 512 thr (8 waves), n-tile 64.
// wave w: nsub = w&1 (32 cols), og = w>>1: og0 -> ot{0,1}, og1..3 -> ot{2..4}.
// V written in tiled layout VT. Grid (64, 8) = 4096 waves.
// ---------------------------------------------------------------------------
__global__ __launch_bounds__(512)
void qkv_kernel(const float* __restrict__ x, const float* __restrict__ gnw,
                const float* __restrict__ gnb, const float* __restrict__ mu_rs,
                const unsigned short* __restrict__ wcatb, const float* __restrict__ bcat,
                unsigned short* __restrict__ qbf, unsigned short* __restrict__ kbf,
                unsigned short* __restrict__ vbf) {
  __shared__ float scs[128], shs[128], bsh[160];
  const int b = blockIdx.y, nb = blockIdx.x * 64, t = threadIdx.x;
  const int w = t >> 6, lane = t & 63, h = lane >> 5, l = lane & 31;
  const int nsub = w & 1, og = w >> 1;
  if (t < 128) {
    float mu = mu_rs[(b * 32 + (t >> 2)) * 2];
    float rs = mu_rs[(b * 32 + (t >> 2)) * 2 + 1];
    float gw = gnw[t], gb = gnb[t];
    scs[t] = rs * gw; shs[t] = gb - mu * rs * gw;
  }
  if (t < 160) bsh[t] = bcat[t];
  __syncthreads();

  const int n = nb + nsub * 32 + l;
  const float* xb = x + ((size_t)b * 128 << 12);
  const int otbase = (og == 0) ? 0 : og + 1; // ot index of acc[0]

  v16f acc[2];
#pragma unroll
  for (int a2 = 0; a2 < 2; ++a2)
#pragma unroll
    for (int r = 0; r < 16; ++r) acc[a2][r] = 0.f;

  for (int ks = 0; ks < 8; ++ks) {
    const int c0 = ks * 16 + 8 * h;
    unsigned fd[4];
#pragma unroll
    for (int p = 0; p < 4; ++p) {
      int ca = c0 + 2 * p, cb2 = ca + 1;
      float h0 = xb[((size_t)ca << 12) + n] * scs[ca] + shs[ca];
      float h1 = xb[((size_t)cb2 << 12) + n] * scs[cb2] + shs[cb2];
      fd[p] = (unsigned)f2bf_rne(h0) | ((unsigned)f2bf_rne(h1) << 16);
    }
    v8s bf = mk8(fd[0], fd[1], fd[2], fd[3]);
    {
      v8s af = *(const v8s*)(wcatb + (otbase * 32 + l) * 128 + ks * 16 + 8 * h);
      acc[0] = __builtin_amdgcn_mfma_f32_32x32x16_bf16(af, bf, acc[0], 0, 0, 0);
    }
    if (og == 0) {
      v8s af = *(const v8s*)(wcatb + (32 + l) * 128 + ks * 16 + 8 * h);
      acc[1] = __builtin_amdgcn_mfma_f32_32x32x16_bf16(af, bf, acc[1], 0, 0, 0);
    }
  }

  // epilogue
  if (og == 0) {
    const size_t nqk = ((size_t)b * 4096 + n) << 4;
#pragma unroll
    for (int r = 0; r < 16; ++r) {
      int o = 4 * h + (r & 3) + 8 * (r >> 2);
      unsigned short bv = f2bf_rne(acc[0][r] + bsh[o]);
      if (o < 16) qbf[nqk + o] = bv; else kbf[nqk + o - 16] = bv;
    }
#pragma unroll
    for (int r = 0; r < 16; ++r) {
      int o = 32 + 4 * h + (r & 3) + 8 * (r >> 2);
      vbf[VT(b, n, o - 32)] = f2bf_rne(acc[1][r] + bsh[o]);
    }
  } else {
#pragma unroll
    for (int r = 0; r < 16; ++r) {
      int o = otbase * 32 + 4 * h + (r & 3) + 8 * (r >> 2);
      vbf[VT(b, n, o - 32)] = f2bf_rne(acc[0][r] + bsh[o]);
    }
  }
}

// ---------------------------------------------------------------------------
// Flash attention. Block 512 thr (8 waves). Wave w = (jc = w>>1, ihalf = w&1):
// owns j in [jc*1024, jc*1024+1024) and i-subtile ihalf (32 rows of the
// 64-row i-tile). Per wave: 1 Q frag, acc[4] (64 f32). Barrier-free j-loop.
// ---------------------------------------------------------------------------
__global__ __launch_bounds__(512)
void attn_kernel(const unsigned short* __restrict__ qbf,
                 const unsigned short* __restrict__ kbf,
                 const unsigned short* __restrict__ vbf,
                 unsigned short* __restrict__ abf) {
  __shared__ float O_lds[128 * 64];
  __shared__ float l_lds[64];
  const int b = blockIdx.y, i0 = blockIdx.x * 64;
  const int t = threadIdx.x;
  const int w = t >> 6, lane = t & 63, h = lane >> 5, l = lane & 31;
  const int ihalf = w & 1, jc = w >> 1;

  for (int idx = t; idx < 128 * 64; idx += 512) O_lds[idx] = 0.f;
  if (t < 64) l_lds[t] = 0.f;
  __syncthreads();

  v16f zc;
#pragma unroll
  for (int r = 0; r < 16; ++r) zc[r] = 0.f;

  // Q B-frag: B[k=d][n=i], n=lane&31, k=8h+e -> b128 from [B,N,16]
  const v8s qf = *(const v8s*)(qbf + (((size_t)(b * 4096 + i0 + ihalf * 32 + l)) << 4) + 8 * h);

  v16f acc[4];
#pragma unroll
  for (int ct = 0; ct < 4; ++ct)
#pragma unroll
    for (int r = 0; r < 16; ++r) acc[ct][r] = 0.f;
  float ls = 0.f;

  const unsigned short* kb_ = kbf + ((size_t)b << 16);
  const unsigned short* vt_ = vbf + ((size_t)b << 19);  // b*256*128*16
  const int jbeg = jc * 1024;

  for (int tile = 0; tile < 32; ++tile) {
    const int j0 = jbeg + tile * 32;
    // K A-frag: A[m=j][k=d] (coalesced 1KB)
    v8s kf = *(const v8s*)(kb_ + (((size_t)(j0 + l)) << 4) + 8 * h);

    v16f st = __builtin_amdgcn_mfma_f32_32x32x16_bf16(kf, qf, zc, 0, 0, 0);
    float p[16];
#pragma unroll
    for (int r = 0; r < 16; ++r) { p[r] = __builtin_amdgcn_exp2f(st[r]); ls += p[r]; }
    unsigned G[8];
#pragma unroll
    for (int g = 0; g < 4; ++g) {
      G[2 * g]     = pack_trunc(p[4 * g + 1], p[4 * g]);
      G[2 * g + 1] = pack_trunc(p[4 * g + 3], p[4 * g + 2]);
    }
    unsigned T[8];
#pragma unroll
    for (int q = 0; q < 8; ++q)
      T[q] = (unsigned)__shfl_xor((int)G[q], 32, 64);

#pragma unroll
    for (int ks = 0; ks < 2; ++ks) {
      // B-frag for PV kstep ks: lo2 = quad g=2ks+h half0, hi2 = same g half1
      unsigned p0 = h ? T[(2 * ks + 1) * 2]     : G[(2 * ks) * 2];
      unsigned p1 = h ? T[(2 * ks + 1) * 2 + 1] : G[(2 * ks) * 2 + 1];
      unsigned p2 = h ? G[(2 * ks + 1) * 2]     : T[(2 * ks) * 2];
      unsigned p3 = h ? G[(2 * ks + 1) * 2 + 1] : T[(2 * ks) * 2 + 1];
      v8s pfv = mk8(p0, p1, p2, p3);
      const size_t chunk = (size_t)((j0 >> 4) + ks) << 7;  // *128
#pragma unroll
      for (int ct = 0; ct < 4; ++ct) {
        // V A-frag: A[m=c][k=j], coalesced 1KB from tiled layout
        v8s vf = *(const v8s*)(vt_ + ((chunk + ct * 32 + l) << 4) + 8 * h);
        acc[ct] = __builtin_amdgcn_mfma_f32_32x32x16_bf16(vf, pfv, acc[ct], 0, 0, 0);
      }
    }
  }

  // combine partials across the 8 waves
  atomicAdd(&l_lds[ihalf * 32 + l], ls);
#pragma unroll
  for (int ct = 0; ct < 4; ++ct)
#pragma unroll
    for (int r = 0; r < 16; ++r) {
      int c = ct * 32 + 4 * h + (r & 3) + 8 * (r >> 2);
      atomicAdd(&O_lds[c * 64 + ihalf * 32 + l], acc[ct][r]);
    }
  __syncthreads();

  // normalize + store O^T -> abf [B,C,N] bf16
  const int i4 = (t & 15) * 4, cb = t >> 4;
  float4 l4 = *(float4*)&l_lds[i4];
  float lix = 1.f / l4.x, liy = 1.f / l4.y, liz = 1.f / l4.z, liw = 1.f / l4.w;
  for (int cc = cb; cc < 128; cc += 32) {
    float4 o4 = *(float4*)&O_lds[cc * 64 + i4];
    unsigned d0 = (unsigned)f2bf_rne(o4.x * lix) | ((unsigned)f2bf_rne(o4.y * liy) << 16);
    unsigned d1 = (unsigned)f2bf_rne(o4.z * liz) | ((unsigned)f2bf_rne(o4.w * liw) << 16);
    uint2 st2; st2.x = d0; st2.y = d1;
    *(uint2*)(abf + (((size_t)(b * 128 + cc)) << 12) + i0 + i4) = st2;
  }
}

// ---------------------------------------------------------------------------
// proj as MFMA GEMM + bias + residual. Block 512 thr (8 waves), n-tile 64:
// nsub = w&1, ot = w>>1 (one 32-row o-tile per wave). Grid (64, 8).
// ---------------------------------------------------------------------------
__global__ __launch_bounds__(512)
void proj_kernel(const unsigned short* __restrict__ abf, const unsigned short* __restrict__ pwb,
                 const float* __restrict__ pb, const float* __restrict__ x,
                 float* __restrict__ out) {
  __shared__ float pbs[128];
  const int b = blockIdx.y, nb = blockIdx.x * 64, t = threadIdx.x;
  const int w = t >> 6, lane = t & 63, h = lane >> 5, l = lane & 31;
  const int nsub = w & 1, ot = w >> 1;
  if (t < 128) pbs[t] = pb[t];
  __syncthreads();

  const int n = nb + nsub * 32 + l;
  const unsigned short* ab = abf + (((size_t)b * 128) << 12);
  v16f acc;
#pragma unroll
  for (int r = 0; r < 16; ++r) acc[r] = 0.f;

  for (int ks = 0; ks < 8; ++ks) {
    const int c0 = ks * 16 + 8 * h;
    unsigned fd[4];
#pragma unroll
    for (int p = 0; p < 4; ++p) {
      unsigned u0 = ab[((size_t)(c0 + 2 * p) << 12) + n];
      unsigned u1 = ab[((size_t)(c0 + 2 * p + 1) << 12) + n];
      fd[p] = u0 | (u1 << 16);
    }
    v8s bf = mk8(fd[0], fd[1], fd[2], fd[3]);
    v8s af = *(const v8s*)(pwb + (ot * 32 + l) * 128 + ks * 16 + 8 * h);
    acc = __builtin_amdgcn_mfma_f32_32x32x16_bf16(af, bf, acc, 0, 0, 0);
  }

#pragma unroll
  for (int r = 0; r < 16; ++r) {
    int e = ot * 32 + 4 * h + (r & 3) + 8 * (r >> 2);
    size_t idx = ((size_t)(b * 128 + e) << 12) + n;
    out[idx] = acc[r] + pbs[e] + x[idx];
  }
}

// ---------------------------------------------------------------------------
extern "C" void kernel_launch(void* const* d_in, const int* in_sizes, int n_in,
                              void* d_out, int out_size, void* d_ws, size_t ws_size,
                              hipStream_t stream) {
  const float* x   = (const float*)d_in[0];
  const float* gnw = (const float*)d_in[1];
  const float* gnb = (const float*)d_in[2];
  const float* qw  = (const float*)d_in[3];
  const float* qb  = (const float*)d_in[4];
  const float* kw  = (const float*)d_in[5];
  const float* kb  = (const float*)d_in[6];
  const float* vw  = (const float*)d_in[7];
  const float* vb  = (const float*)d_in[8];
  const float* pw  = (const float*)d_in[9];
  const float* pb  = (const float*)d_in[10];
  float* out = (float*)d_out;
  char* ws = (char*)d_ws;

  float* mu_rs = (float*)(ws + WSB_MURS);
  unsigned short* wcatb = (unsigned short*)(ws + WSB_WCATB);
  float* bcat = (float*)(ws + WSB_BCAT);
  unsigned short* pwb = (unsigned short*)(ws + WSB_PWB);
  unsigned short* qbf = (unsigned short*)(ws + WSB_QBF);
  unsigned short* kbf = (unsigned short*)(ws + WSB_KBF);
  unsigned short* vbf = (unsigned short*)(ws + WSB_VBF);
  unsigned short* abf = (unsigned short*)(ws + WSB_ABF);

  hipLaunchKernelGGL(prep_kernel, dim3(145), dim3(256), 0, stream,
                     qw, qb, kw, kb, vw, vb, pw, wcatb, bcat, pwb);
  hipLaunchKernelGGL(gn_stats_kernel, dim3(256), dim3(512), 0, stream, x, mu_rs);
  hipLaunchKernelGGL(qkv_kernel, dim3(64, 8), dim3(512), 0, stream,
                     x, gnw, gnb, mu_rs, wcatb, bcat, qbf, kbf, vbf);
  hipLaunchKernelGGL(attn_kernel, dim3(64, 8), dim3(512), 0, stream,
                     qbf, kbf, vbf, abf);
  hipLaunchKernelGGL(proj_kernel, dim3(64, 8), dim3(512), 0, stream,
                     abf, pwb, pb, x, out);
}

// Round 6
// 281.420 us; speedup vs baseline: 3.3704x; 1.0124x over previous
//
#include <hip/hip_runtime.h>
#include <math.h>

// B=8, C=128, N=4096, d=16, groups=32
// attn: S^T = K @ Q^T via mfma_32x32x16_bf16 (coalesced global frags, no LDS),
//       P = exp2(S^T) (no-max softmax; Q pre-scaled by 0.25*log2e),
//       P^T B-frags built in-register via half-wave shfl_xor(32) exchange,
//       O^T = V @ P^T with V in TILED layout vt[b][j>>4][c][j&15] (coalesced).
// R6: ALL per-batch kernels use 1D grids with batch = linear_block_id % 8 so
//     the round-robin workgroup->XCD dispatch pins batch b to XCD b. Per-XCD
//     L2 (4 MB) then holds its batch's V+K+Q hot set (~1.3 MB) -> V re-reads
//     come from L2, not L3/HBM. (R2/R3/R5 all plateaued ~160-180 us with 8
//     batches interleaved on every XCD = 9 MB hot set thrashing 4 MB L2.)

typedef short v8s __attribute__((ext_vector_type(8)));   // 8 bf16 = 4 VGPRs
typedef float v16f __attribute__((ext_vector_type(16))); // 32x32 acc

__device__ __forceinline__ unsigned short f2bf_rne(float f) {
  unsigned u = __float_as_uint(f);
  u += 0x7fffu + ((u >> 16) & 1u);
  return (unsigned short)(u >> 16);
}

__device__ __forceinline__ v8s mk8(unsigned a, unsigned b, unsigned c, unsigned d) {
  union { unsigned u[4]; v8s s; } x;
  x.u[0] = a; x.u[1] = b; x.u[2] = c; x.u[3] = d;
  return x.s;
}

// pack two fp32 -> dword of 2 bf16 (truncation) in ONE v_perm_b32
__device__ __forceinline__ unsigned pack_trunc(float hi, float lo) {
  return __builtin_amdgcn_perm(__float_as_uint(hi), __float_as_uint(lo), 0x07060302u);
}

// tiled V element index: [b][j>>4][c][j&15]
#define VT(b, n, c) (((((size_t)(b) * 256 + ((n) >> 4)) << 7) + (c)) * 16 + ((n) & 15))

// ws byte offsets
#define WSB_MURS   0u
#define WSB_WCATB  4096u       // 160*128 bf16 = 40960
#define WSB_BCAT   49152u      // 160 f32
#define WSB_PWB    65536u      // 128*128 bf16 = 32768
#define WSB_QBF    131072u     // 8*4096*16 bf16 = 1 MB
#define WSB_KBF    1310720u    // 1 MB
#define WSB_VBF    2621440u    // 8 MB (tiled)
#define WSB_ABF    11534336u   // 8 MB

// ---------------------------------------------------------------------------
__global__ void prep_kernel(const float* __restrict__ qw, const float* __restrict__ qb,
                            const float* __restrict__ kw, const float* __restrict__ kb,
                            const float* __restrict__ vw, const float* __restrict__ vb,
                            const float* __restrict__ pw,
                            unsigned short* __restrict__ wcatb, float* __restrict__ bcat,
                            unsigned short* __restrict__ pwb) {
  const float qs = 0.36067376022224085f;  // 0.25 * log2(e)
  int idx = blockIdx.x * 256 + threadIdx.x;
  if (idx < 160 * 128) {
    int o = idx >> 7, c = idx & 127;
    float val;
    if (o < 16)       val = qw[o * 128 + c] * qs;
    else if (o < 32)  val = kw[(o - 16) * 128 + c];
    else              val = vw[(o - 32) * 128 + c];
    wcatb[idx] = f2bf_rne(val);
  } else if (idx < 160 * 128 + 160) {
    int o = idx - 160 * 128;
    bcat[o] = (o < 16) ? qb[o] * qs : (o < 32) ? kb[o - 16] : vb[o - 32];
  } else if (idx < 160 * 128 + 160 + 128 * 128) {
    int j = idx - (160 * 128 + 160);
    pwb[j] = f2bf_rne(pw[j]);
  }
}

// ---------------------------------------------------------------------------
__global__ __launch_bounds__(512)
void gn_stats_kernel(const float* __restrict__ x, float* __restrict__ mu_rs) {
  const int id = blockIdx.x;              // XCD swizzle: batch = id & 7
  const int bg = (id & 7) * 32 + (id >> 3);
  const float4* xp = (const float4*)(x + (size_t)bg * 16384);
  float s = 0.f, ss = 0.f;
  for (int i = threadIdx.x; i < 4096; i += 512) {
    float4 v = xp[i];
    s  += v.x + v.y + v.z + v.w;
    ss += v.x * v.x + v.y * v.y + v.z * v.z + v.w * v.w;
  }
  for (int off = 32; off > 0; off >>= 1) {
    s  += __shfl_down(s, off, 64);
    ss += __shfl_down(ss, off, 64);
  }
  __shared__ float red[16];
  int lane = threadIdx.x & 63, wid = threadIdx.x >> 6;
  if (lane == 0) { red[wid * 2] = s; red[wid * 2 + 1] = ss; }
  __syncthreads();
  if (threadIdx.x == 0) {
    float S = 0.f, SS = 0.f;
    for (int w = 0; w < 8; ++w) { S += red[w * 2]; SS += red[w * 2 + 1]; }
    float mu  = S * (1.0f / 16384.0f);
    float var = SS * (1.0f / 16384.0f) - mu * mu;
    float rs  = rsqrtf(var + 1e-5f);
    mu_rs[bg * 2]     = mu;
    mu_rs[bg * 2 + 1] = rs;
  }
}

// ---------------------------------------------------------------------------
// QKV as MFMA GEMM, GN fused. Block 512 thr (8 waves), n-tile 64.
// wave w: nsub = w&1 (32 cols), og = w>>1: og0 -> ot{0,1}, og1..3 -> ot{2..4}.
// V written in tiled layout VT. Grid 512 1D, batch = id & 7 (XCD-pinned).
// ---------------------------------------------------------------------------
__global__ __launch_bounds__(512)
void qkv_kernel(const float* __restrict__ x, const float* __restrict__ gnw,
                const float* __restrict__ gnb, const float* __restrict__ mu_rs,
                const unsigned short* __restrict__ wcatb, const float* __restrict__ bcat,
                unsigned short* __restrict__ qbf, unsigned short* __restrict__ kbf,
                unsigned short* __restrict__ vbf) {
  __shared__ float scs[128], shs[128], bsh[160];
  const int id = blockIdx.x;
  const int b = id & 7, nb = (id >> 3) << 6;   // XCD-pinned batch
  const int t = threadIdx.x;
  const int w = t >> 6, lane = t & 63, h = lane >> 5, l = lane & 31;
  const int nsub = w & 1, og = w >> 1;
  if (t < 128) {
    float mu = mu_rs[(b * 32 + (t >> 2)) * 2];
    float rs = mu_rs[(b * 32 + (t >> 2)) * 2 + 1];
    float gw = gnw[t], gb = gnb[t];
    scs[t] = rs * gw; shs[t] = gb - mu * rs * gw;
  }
  if (t < 160) bsh[t] = bcat[t];
  __syncthreads();

  const int n = nb + nsub * 32 + l;
  const float* xb = x + ((size_t)b * 128 << 12);
  const int otbase = (og == 0) ? 0 : og + 1; // ot index of acc[0]

  v16f acc[2];
#pragma unroll
  for (int a2 = 0; a2 < 2; ++a2)
#pragma unroll
    for (int r = 0; r < 16; ++r) acc[a2][r] = 0.f;

  for (int ks = 0; ks < 8; ++ks) {
    const int c0 = ks * 16 + 8 * h;
    unsigned fd[4];
#pragma unroll
    for (int p = 0; p < 4; ++p) {
      int ca = c0 + 2 * p, cb2 = ca + 1;
      float h0 = xb[((size_t)ca << 12) + n] * scs[ca] + shs[ca];
      float h1 = xb[((size_t)cb2 << 12) + n] * scs[cb2] + shs[cb2];
      fd[p] = (unsigned)f2bf_rne(h0) | ((unsigned)f2bf_rne(h1) << 16);
    }
    v8s bf = mk8(fd[0], fd[1], fd[2], fd[3]);
    {
      v8s af = *(const v8s*)(wcatb + (otbase * 32 + l) * 128 + ks * 16 + 8 * h);
      acc[0] = __builtin_amdgcn_mfma_f32_32x32x16_bf16(af, bf, acc[0], 0, 0, 0);
    }
    if (og == 0) {
      v8s af = *(const v8s*)(wcatb + (32 + l) * 128 + ks * 16 + 8 * h);
      acc[1] = __builtin_amdgcn_mfma_f32_32x32x16_bf16(af, bf, acc[1], 0, 0, 0);
    }
  }

  // epilogue
  if (og == 0) {
    const size_t nqk = ((size_t)b * 4096 + n) << 4;
#pragma unroll
    for (int r = 0; r < 16; ++r) {
      int o = 4 * h + (r & 3) + 8 * (r >> 2);
      unsigned short bv = f2bf_rne(acc[0][r] + bsh[o]);
      if (o < 16) qbf[nqk + o] = bv; else kbf[nqk + o - 16] = bv;
    }
#pragma unroll
    for (int r = 0; r < 16; ++r) {
      int o = 32 + 4 * h + (r & 3) + 8 * (r >> 2);
      vbf[VT(b, n, o - 32)] = f2bf_rne(acc[1][r] + bsh[o]);
    }
  } else {
#pragma unroll
    for (int r = 0; r < 16; ++r) {
      int o = otbase * 32 + 4 * h + (r & 3) + 8 * (r >> 2);
      vbf[VT(b, n, o - 32)] = f2bf_rne(acc[0][r] + bsh[o]);
    }
  }
}

// ---------------------------------------------------------------------------
// Flash attention. Block 512 thr (8 waves). Wave w = (jc = w>>1, ihalf = w&1):
// owns j in [jc*1024, jc*1024+1024) and i-subtile ihalf. Barrier-free j-loop.
// Grid 512 1D, batch = id & 7 (XCD-pinned: batch b's V/K/Q live in XCD b's L2).
// ---------------------------------------------------------------------------
__global__ __launch_bounds__(512)
void attn_kernel(const unsigned short* __restrict__ qbf,
                 const unsigned short* __restrict__ kbf,
                 const unsigned short* __restrict__ vbf,
                 unsigned short* __restrict__ abf) {
  __shared__ float O_lds[128 * 64];
  __shared__ float l_lds[64];
  const int id = blockIdx.x;
  const int b = id & 7, i0 = (id >> 3) << 6;   // XCD-pinned batch
  const int t = threadIdx.x;
  const int w = t >> 6, lane = t & 63, h = lane >> 5, l = lane & 31;
  const int ihalf = w & 1, jc = w >> 1;

  for (int idx = t; idx < 128 * 64; idx += 512) O_lds[idx] = 0.f;
  if (t < 64) l_lds[t] = 0.f;
  __syncthreads();

  v16f zc;
#pragma unroll
  for (int r = 0; r < 16; ++r) zc[r] = 0.f;

  // Q B-frag: B[k=d][n=i], n=lane&31, k=8h+e -> b128 from [B,N,16]
  const v8s qf = *(const v8s*)(qbf + (((size_t)(b * 4096 + i0 + ihalf * 32 + l)) << 4) + 8 * h);

  v16f acc[4];
#pragma unroll
  for (int ct = 0; ct < 4; ++ct)
#pragma unroll
    for (int r = 0; r < 16; ++r) acc[ct][r] = 0.f;
  float ls = 0.f;

  const unsigned short* kb_ = kbf + ((size_t)b << 16);
  const unsigned short* vt_ = vbf + ((size_t)b << 19);  // b*256*128*16
  const int jbeg = jc * 1024;

  for (int tile = 0; tile < 32; ++tile) {
    const int j0 = jbeg + tile * 32;
    // K A-frag: A[m=j][k=d] (coalesced 1KB)
    v8s kf = *(const v8s*)(kb_ + (((size_t)(j0 + l)) << 4) + 8 * h);

    v16f st = __builtin_amdgcn_mfma_f32_32x32x16_bf16(kf, qf, zc, 0, 0, 0);
    float p[16];
#pragma unroll
    for (int r = 0; r < 16; ++r) { p[r] = __builtin_amdgcn_exp2f(st[r]); ls += p[r]; }
    unsigned G[8];
#pragma unroll
    for (int g = 0; g < 4; ++g) {
      G[2 * g]     = pack_trunc(p[4 * g + 1], p[4 * g]);
      G[2 * g + 1] = pack_trunc(p[4 * g + 3], p[4 * g + 2]);
    }
    unsigned T[8];
#pragma unroll
    for (int q = 0; q < 8; ++q)
      T[q] = (unsigned)__shfl_xor((int)G[q], 32, 64);

#pragma unroll
    for (int ks = 0; ks < 2; ++ks) {
      // B-frag for PV kstep ks: lo2 = quad g=2ks+h half0, hi2 = same g half1
      unsigned p0 = h ? T[(2 * ks + 1) * 2]     : G[(2 * ks) * 2];
      unsigned p1 = h ? T[(2 * ks + 1) * 2 + 1] : G[(2 * ks) * 2 + 1];
      unsigned p2 = h ? G[(2 * ks + 1) * 2]     : T[(2 * ks) * 2];
      unsigned p3 = h ? G[(2 * ks + 1) * 2 + 1] : T[(2 * ks) * 2 + 1];
      v8s pfv = mk8(p0, p1, p2, p3);
      const size_t chunk = (size_t)((j0 >> 4) + ks) << 7;  // *128
#pragma unroll
      for (int ct = 0; ct < 4; ++ct) {
        // V A-frag: A[m=c][k=j], coalesced 1KB from tiled layout
        v8s vf = *(const v8s*)(vt_ + ((chunk + ct * 32 + l) << 4) + 8 * h);
        acc[ct] = __builtin_amdgcn_mfma_f32_32x32x16_bf16(vf, pfv, acc[ct], 0, 0, 0);
      }
    }
  }

  // combine partials across the 8 waves
  atomicAdd(&l_lds[ihalf * 32 + l], ls);
#pragma unroll
  for (int ct = 0; ct < 4; ++ct)
#pragma unroll
    for (int r = 0; r < 16; ++r) {
      int c = ct * 32 + 4 * h + (r & 3) + 8 * (r >> 2);
      atomicAdd(&O_lds[c * 64 + ihalf * 32 + l], acc[ct][r]);
    }
  __syncthreads();

  // normalize + store O^T -> abf [B,C,N] bf16
  const int i4 = (t & 15) * 4, cb = t >> 4;
  float4 l4 = *(float4*)&l_lds[i4];
  float lix = 1.f / l4.x, liy = 1.f / l4.y, liz = 1.f / l4.z, liw = 1.f / l4.w;
  for (int cc = cb; cc < 128; cc += 32) {
    float4 o4 = *(float4*)&O_lds[cc * 64 + i4];
    unsigned d0 = (unsigned)f2bf_rne(o4.x * lix) | ((unsigned)f2bf_rne(o4.y * liy) << 16);
    unsigned d1 = (unsigned)f2bf_rne(o4.z * liz) | ((unsigned)f2bf_rne(o4.w * liw) << 16);
    uint2 st2; st2.x = d0; st2.y = d1;
    *(uint2*)(abf + (((size_t)(b * 128 + cc)) << 12) + i0 + i4) = st2;
  }
}

// ---------------------------------------------------------------------------
// proj as MFMA GEMM + bias + residual. Block 512 thr (8 waves), n-tile 64:
// nsub = w&1, ot = w>>1. Grid 512 1D, batch = id & 7 (XCD-pinned: reads abf
// from the same XCD's L2 that attn wrote it to).
// ---------------------------------------------------------------------------
__global__ __launch_bounds__(512)
void proj_kernel(const unsigned short* __restrict__ abf, const unsigned short* __restrict__ pwb,
                 const float* __restrict__ pb, const float* __restrict__ x,
                 float* __restrict__ out) {
  __shared__ float pbs[128];
  const int id = blockIdx.x;
  const int b = id & 7, nb = (id >> 3) << 6;   // XCD-pinned batch
  const int t = threadIdx.x;
  const int w = t >> 6, lane = t & 63, h = lane >> 5, l = lane & 31;
  const int nsub = w & 1, ot = w >> 1;
  if (t < 128) pbs[t] = pb[t];
  __syncthreads();

  const int n = nb + nsub * 32 + l;
  const unsigned short* ab = abf + (((size_t)b * 128) << 12);
  v16f acc;
#pragma unroll
  for (int r = 0; r < 16; ++r) acc[r] = 0.f;

  for (int ks = 0; ks < 8; ++ks) {
    const int c0 = ks * 16 + 8 * h;
    unsigned fd[4];
#pragma unroll
    for (int p = 0; p < 4; ++p) {
      unsigned u0 = ab[((size_t)(c0 + 2 * p) << 12) + n];
      unsigned u1 = ab[((size_t)(c0 + 2 * p + 1) << 12) + n];
      fd[p] = u0 | (u1 << 16);
    }
    v8s bf = mk8(fd[0], fd[1], fd[2], fd[3]);
    v8s af = *(const v8s*)(pwb + (ot * 32 + l) * 128 + ks * 16 + 8 * h);
    acc = __builtin_amdgcn_mfma_f32_32x32x16_bf16(af, bf, acc, 0, 0, 0);
  }

#pragma unroll
  for (int r = 0; r < 16; ++r) {
    int e = ot * 32 + 4 * h + (r & 3) + 8 * (r >> 2);
    size_t idx = ((size_t)(b * 128 + e) << 12) + n;
    out[idx] = acc[r] + pbs[e] + x[idx];
  }
}

// ---------------------------------------------------------------------------
extern "C" void kernel_launch(void* const* d_in, const int* in_sizes, int n_in,
                              void* d_out, int out_size, void* d_ws, size_t ws_size,
                              hipStream_t stream) {
  const float* x   = (const float*)d_in[0];
  const float* gnw = (const float*)d_in[1];
  const float* gnb = (const float*)d_in[2];
  const float* qw  = (const float*)d_in[3];
  const float* qb  = (const float*)d_in[4];
  const float* kw  = (const float*)d_in[5];
  const float* kb  = (const float*)d_in[6];
  const float* vw  = (const float*)d_in[7];
  const float* vb  = (const float*)d_in[8];
  const float* pw  = (const float*)d_in[9];
  const float* pb  = (const float*)d_in[10];
  float* out = (float*)d_out;
  char* ws = (char*)d_ws;

  float* mu_rs = (float*)(ws + WSB_MURS);
  unsigned short* wcatb = (unsigned short*)(ws + WSB_WCATB);
  float* bcat = (float*)(ws + WSB_BCAT);
  unsigned short* pwb = (unsigned short*)(ws + WSB_PWB);
  unsigned short* qbf = (unsigned short*)(ws + WSB_QBF);
  unsigned short* kbf = (unsigned short*)(ws + WSB_KBF);
  unsigned short* vbf = (unsigned short*)(ws + WSB_VBF);
  unsigned short* abf = (unsigned short*)(ws + WSB_ABF);

  hipLaunchKernelGGL(prep_kernel, dim3(145), dim3(256), 0, stream,
                     qw, qb, kw, kb, vw, vb, pw, wcatb, bcat, pwb);
  hipLaunchKernelGGL(gn_stats_kernel, dim3(256), dim3(512), 0, stream, x, mu_rs);
  hipLaunchKernelGGL(qkv_kernel, dim3(512), dim3(512), 0, stream,
                     x, gnw, gnb, mu_rs, wcatb, bcat, qbf, kbf, vbf);
  hipLaunchKernelGGL(attn_kernel, dim3(512), dim3(512), 0, stream,
                     qbf, kbf, vbf, abf);
  hipLaunchKernelGGL(proj_kernel, dim3(512), dim3(512), 0, stream,
                     abf, pwb, pb, x, out);
}